// Round 8
// baseline (482.653 us; speedup 1.0000x reference)
//
#include <hip/hip_runtime.h>
#include <cstdint>
#include <cstddef>

// Problem constants (match reference)
#define BTOT    4096
#define SRCLEN  128
#define INDIM   16
#define HDIM    64
#define SEQLEN  100
#define MEANS_N (BTOT * SEQLEN * 4)   // 1638400

// ---------- helpers ----------
__device__ __forceinline__ float sigmoidf_(float x) {
    return __builtin_amdgcn_rcpf(1.0f + __expf(-x));
}
__device__ __forceinline__ float tanhf_(float x) {
    float e = __expf(2.0f * x);
    return 1.0f - 2.0f * __builtin_amdgcn_rcpf(e + 1.0f);
}
// gelu via Abramowitz-Stegun 7.1.26 erf (|err| < 1.5e-7)
__device__ __forceinline__ float gelu_fast(float x) {
    float z = fabsf(x) * 0.70710678118654752440f;
    float t = __builtin_amdgcn_rcpf(1.0f + 0.3275911f * z);
    float p = t * (0.254829592f +
              t * (-0.284496736f +
              t * (1.421413741f +
              t * (-1.453152027f +
              t * 1.061405429f))));
    float er = 1.0f - p * __expf(-z * z);
    er = copysignf(er, x);
    return 0.5f * x * (1.0f + er);
}

// ---------- bf16 split helpers (bf16x3 emulated-fp32 MFMA) ----------
typedef __attribute__((ext_vector_type(8))) short s8v;   // 8 bf16 (4 VGPRs)
typedef __attribute__((ext_vector_type(4))) float f4v;   // 4 fp32

__device__ __forceinline__ unsigned short f2bf(float x) {  // RTNE float -> bf16 bits
    unsigned u = __float_as_uint(x);
    unsigned r = (u + 0x7FFFu + ((u >> 16) & 1u)) >> 16;
    return (unsigned short)r;
}
__device__ __forceinline__ float bf2f(unsigned short b) {
    return __uint_as_float(((unsigned)b) << 16);
}
__device__ __forceinline__ void split2(float4 a, float4 b, s8v& hi, s8v& lo) {
    float v[8] = {a.x, a.y, a.z, a.w, b.x, b.y, b.z, b.w};
    #pragma unroll
    for (int j = 0; j < 8; ++j) {
        unsigned short h = f2bf(v[j]);
        hi[j] = (short)h;
        lo[j] = (short)f2bf(v[j] - bf2f(h));
    }
}
__device__ __forceinline__ void split8(const float* v, s8v& hi, s8v& lo) {
    #pragma unroll
    for (int j = 0; j < 8; ++j) {
        unsigned short h = f2bf(v[j]);
        hi[j] = (short)h;
        lo[j] = (short)f2bf(v[j] - bf2f(h));
    }
}
__device__ __forceinline__ void load_bfrag(const float* p, s8v& hi, s8v& lo) {
    float4 a = *(const float4*)p;
    float4 b = *(const float4*)(p + 4);
    split2(a, b, hi, lo);
}

// permlane32_swap merge: lanes 0-31 keep own_lo, lanes 32-63 get send_hi
// from lane-32. Single VALU op.
typedef __attribute__((ext_vector_type(2))) unsigned int u2v;
__device__ __forceinline__ float half_merge(float own_lo, float send_hi) {
    u2v r = __builtin_amdgcn_permlane32_swap(__float_as_uint(own_lo),
                                             __float_as_uint(send_hi),
                                             false, false);
    return __uint_as_float(r[0]);
}

#define MFMA16(a, b, c) __builtin_amdgcn_mfma_f32_16x16x32_bf16((a), (b), (c), 0, 0, 0)

// =====================================================================
// FULLY FUSED encoder + decoder + heads (R7 structure).
// R8 fix: stage2 outputs go to an LDS staging buffer (16-step chunks,
// parity double-buffered) and are flushed with coalesced contiguous
// writes every 16 steps. R7's per-step scattered 16B/40B stores caused
// 8x write amplification (WRITE_SIZE 197 MB, FETCH 105 MB -> HBM-bound
// 406 us). Values are bitwise identical; only the store path changes.
// =====================================================================
__global__ __launch_bounds__(256, 2) void fused_gru_kernel(
    const float* __restrict__ x,
    const float* __restrict__ eWih, const float* __restrict__ ebih,
    const float* __restrict__ eWhh, const float* __restrict__ ebhh,
    const float* __restrict__ dWih, const float* __restrict__ dbih,
    const float* __restrict__ dWhh, const float* __restrict__ dbhh,
    const float* __restrict__ outW, const float* __restrict__ outb,
    const float* __restrict__ embW, const float* __restrict__ embb,
    const float* __restrict__ trg,
    const float* __restrict__ mW1, const float* __restrict__ mb1,
    const float* __restrict__ mW2, const float* __restrict__ mb2,
    const float* __restrict__ cW1, const float* __restrict__ cb1,
    const float* __restrict__ cW2, const float* __restrict__ cb2,
    float* __restrict__ out)
{
    const int tid  = threadIdx.x;
    const int lane = tid & 63;
    const int w    = tid >> 6;     // wave 0..3
    const int col  = lane & 15;
    const int q    = lane >> 4;
    const int u    = w * 16 + col;
    const int b0   = blockIdx.x * 8;
    // post-rebalance batch row for item j: rows {0,1},{4,5},{2,3},{6,7} for q=0..3
    const int rj0  = (q & 1) * 4 + ((q >> 1) << 1);

    __shared__ __align__(16) unsigned short hiL[2][16][72];
    __shared__ __align__(16) unsigned short loL[2][16][72];
    // enc x tile: [tl][batch 0..7 | zero-row 8][dim]
    __shared__ __align__(16) unsigned short xhi_l[64][9][16];
    __shared__ __align__(16) unsigned short xlo_l[64][9][16];
    // dec helpers
    __shared__ float outW_l[16][64];
    __shared__ float init_l[8][16];
    // heads pipeline buffers (parity double-buffered)
    __shared__ __align__(16) float o_sl[2][8][16];
    __shared__ __align__(16) unsigned short Hm_hi[2][8][72];
    __shared__ __align__(16) unsigned short Hm_lo[2][8][72];
    __shared__ __align__(16) unsigned short Hc_hi[2][8][72];
    __shared__ __align__(16) unsigned short Hc_lo[2][8][72];
    // output staging: 16-step chunks, parity double-buffered (R8)
    __shared__ __align__(16) float om_st[2][8][16][4];    // [buf][batch][sc][col]
    __shared__ __align__(16) float cv_st[2][8][16][10];   // [buf][batch][sc][col]

    // ---- stage dec LDS (outW, init_in) ----
    for (int i = tid; i < 16 * 64; i += 256) outW_l[i >> 6][i & 63] = outW[i];
    if (tid < 128) {
        int b = tid >> 4, jj = tid & 15;
        float s = embb[jj];
        #pragma unroll
        for (int s4 = 0; s4 < 4; ++s4)
            s = fmaf(embW[jj * 4 + s4], trg[(size_t)(b0 + b) * 4 + s4], s);
        init_l[b][jj] = s;
    }

    // ---- enc init: zero both h buffers (rows 8-15 stay zero forever) ----
    for (int i = tid; i < 2 * 16 * 72; i += 256) {
        ((unsigned short*)hiL)[i] = 0;
        ((unsigned short*)loL)[i] = 0;
    }
    for (int i = tid; i < 64 * 16; i += 256) {
        xhi_l[i >> 4][8][i & 15] = 0;
        xlo_l[i >> 4][8][i & 15] = 0;
    }

    // stage one 64-step chunk of x, pre-split into bf16 hi/lo
    auto stage_x = [&](int c) {
        #pragma unroll
        for (int k = 0; k < 8; ++k) {
            int f   = tid + k * 256;
            int b   = f >> 8;
            int rem = f & 255;
            int tl  = rem >> 2;
            int d4  = (rem & 3) << 2;
            const float* xp = x + ((size_t)(b0 + b) * SRCLEN + (c * 64 + tl)) * INDIM + d4;
            float4 v = *(const float4*)xp;
            float vv[4] = {v.x, v.y, v.z, v.w};
            unsigned short hh[4], ll[4];
            #pragma unroll
            for (int j = 0; j < 4; ++j) {
                hh[j] = f2bf(vv[j]);
                ll[j] = f2bf(vv[j] - bf2f(hh[j]));
            }
            *(ushort4*)&xhi_l[tl][b][d4] = make_ushort4(hh[0], hh[1], hh[2], hh[3]);
            *(ushort4*)&xlo_l[tl][b][d4] = make_ushort4(ll[0], ll[1], ll[2], ll[3]);
        }
    };

    const s8v z8 = {0, 0, 0, 0, 0, 0, 0, 0};
    const f4v z4 = {0.0f, 0.0f, 0.0f, 0.0f};

    // ================= ENCODER PHASE (verified) =================
    float hold2e[2];
    {
        s8v brh[3], brl[3], bzh[3], bzl[3], bnhh[2], bnhl[2], bnxh, bnxl;
        load_bfrag(eWhh + (size_t)u * 64 + q * 8,              brh[0], brl[0]);
        load_bfrag(eWhh + (size_t)u * 64 + 32 + q * 8,         brh[1], brl[1]);
        load_bfrag(eWhh + (size_t)(64 + u) * 64 + q * 8,       bzh[0], bzl[0]);
        load_bfrag(eWhh + (size_t)(64 + u) * 64 + 32 + q * 8,  bzh[1], bzl[1]);
        load_bfrag(eWhh + (size_t)(128 + u) * 64 + q * 8,      bnhh[0], bnhl[0]);
        load_bfrag(eWhh + (size_t)(128 + u) * 64 + 32 + q * 8, bnhh[1], bnhl[1]);
        if (q < 2) {
            load_bfrag(eWih + (size_t)u * 16 + q * 8,         brh[2], brl[2]);
            load_bfrag(eWih + (size_t)(64 + u) * 16 + q * 8,  bzh[2], bzl[2]);
            load_bfrag(eWih + (size_t)(128 + u) * 16 + q * 8, bnxh, bnxl);
        } else {
            brh[2] = z8; brl[2] = z8; bzh[2] = z8; bzl[2] = z8; bnxh = z8; bnxl = z8;
        }

        const float br   = ebih[u] + ebhh[u];
        const float bz   = ebih[u + 64] + ebhh[u + 64];
        const float bnx  = ebih[u + 128];
        const float bnh  = ebhh[u + 128];

        const int xb   = (q < 2) ? (col & 7) : 8;
        const int xoff = (q & 1) * 8;
        const unsigned short* xh_base = &xhi_l[0][xb][xoff];
        const unsigned short* xl_base = &xlo_l[0][xb][xoff];

        stage_x(0);
        hold2e[0] = 0.0f; hold2e[1] = 0.0f;
        __syncthreads();

        int cur = 0;
        for (int t = 0; t < SRCLEN; ++t) {
            if (t == 64) {
                stage_x(1);
                __syncthreads();
            }
            const int tl = t & 63;

            const s8v xh = *(const s8v*)(xh_base + (size_t)tl * 144);
            const s8v xl = *(const s8v*)(xl_base + (size_t)tl * 144);

            const s8v ah0 = *(const s8v*)&hiL[cur][col][q * 8];
            const s8v al0 = *(const s8v*)&loL[cur][col][q * 8];
            const s8v ah1 = *(const s8v*)&hiL[cur][col][32 + q * 8];
            const s8v al1 = *(const s8v*)&loL[cur][col][32 + q * 8];

            f4v accr, accz, accnh, accnx;
            accr  = MFMA16(ah0, brh[0], z4);
            accz  = MFMA16(ah0, bzh[0], z4);
            accnh = MFMA16(ah0, bnhh[0], z4);
            accr  = MFMA16(ah0, brl[0], accr);
            accz  = MFMA16(ah0, bzl[0], accz);
            accnh = MFMA16(ah0, bnhl[0], accnh);
            accr  = MFMA16(al0, brh[0], accr);
            accz  = MFMA16(al0, bzh[0], accz);
            accnh = MFMA16(al0, bnhh[0], accnh);
            accr  = MFMA16(ah1, brh[1], accr);
            accz  = MFMA16(ah1, bzh[1], accz);
            accnh = MFMA16(ah1, bnhh[1], accnh);
            accr  = MFMA16(ah1, brl[1], accr);
            accz  = MFMA16(ah1, bzl[1], accz);
            accnh = MFMA16(ah1, bnhl[1], accnh);
            accr  = MFMA16(al1, brh[1], accr);
            accz  = MFMA16(al1, bzh[1], accz);
            accnh = MFMA16(al1, bnhh[1], accnh);
            accr  = MFMA16(xh, brh[2], accr);
            accz  = MFMA16(xh, bzh[2], accz);
            accnx = MFMA16(xh, bnxh, z4);
            accr  = MFMA16(xh, brl[2], accr);
            accz  = MFMA16(xh, bzl[2], accz);
            accnx = MFMA16(xh, bnxl, accnx);
            accr  = MFMA16(xl, brh[2], accr);
            accz  = MFMA16(xl, bzh[2], accz);
            accnx = MFMA16(xl, bnxh, accnx);

            float pr[2], pz[2], pnh[2], pnx[2];
            pr[0]  = half_merge(accr[0],  accr[2]);
            pr[1]  = half_merge(accr[1],  accr[3]);
            pz[0]  = half_merge(accz[0],  accz[2]);
            pz[1]  = half_merge(accz[1],  accz[3]);
            pnh[0] = half_merge(accnh[0], accnh[2]);
            pnh[1] = half_merge(accnh[1], accnh[3]);
            pnx[0] = half_merge(accnx[0], accnx[2]);
            pnx[1] = half_merge(accnx[1], accnx[3]);

            const int nxt = cur ^ 1;
            #pragma unroll
            for (int j = 0; j < 2; ++j) {
                float r  = sigmoidf_(pr[j] + br);
                float zz = sigmoidf_(pz[j] + bz);
                float n  = tanhf_(pnx[j] + bnx + r * (pnh[j] + bnh));
                float h  = (1.0f - zz) * n + zz * hold2e[j];
                hold2e[j] = h;
                unsigned short hh = f2bf(h);
                hiL[nxt][rj0 + j][u] = hh;
                loL[nxt][rj0 + j][u] = f2bf(h - bf2f(hh));
            }
            __syncthreads();
            cur ^= 1;
        }
    }

    // ================= DECODER + HEADS PHASE =================
    {
        float hold2[2] = {hold2e[0], hold2e[1]};

        float wh_r[16], wh_z[16], wh_n[16];
        #pragma unroll
        for (int c = 0; c < 2; ++c)
            #pragma unroll
            for (int jj = 0; jj < 8; ++jj) {
                int k = c * 32 + q * 8 + jj;
                wh_r[c * 8 + jj] = dWhh[(size_t)u * 64 + k];
                wh_z[c * 8 + jj] = dWhh[(size_t)(64 + u) * 64 + k];
                wh_n[c * 8 + jj] = dWhh[(size_t)(128 + u) * 64 + k];
            }
        float wi_r[16], wi_z[16], wi_n[16];
        #pragma unroll
        for (int j = 0; j < 16; ++j) {
            wi_r[j] = dWih[(size_t)u * 16 + j];
            wi_z[j] = dWih[(size_t)(64 + u) * 16 + j];
            wi_n[j] = dWih[(size_t)(128 + u) * 16 + j];
        }

        float m_r[16], m_z[16], c_in[16];
        #pragma unroll
        for (int c = 0; c < 2; ++c)
            #pragma unroll
            for (int jj = 0; jj < 8; ++jj) {
                int k = c * 32 + q * 8 + jj;
                float sr = 0.0f, sz = 0.0f, sn = 0.0f;
                #pragma unroll
                for (int j = 0; j < 16; ++j) {
                    float ow = outW_l[j][k];
                    sr = fmaf(wi_r[j], ow, sr);
                    sz = fmaf(wi_z[j], ow, sz);
                    sn = fmaf(wi_n[j], ow, sn);
                }
                m_r[c * 8 + jj]  = wh_r[c * 8 + jj] + sr;
                m_z[c * 8 + jj]  = wh_z[c * 8 + jj] + sz;
                c_in[c * 8 + jj] = sn;
            }

        s8v mrh[2], mrl[2], mzh[2], mzl[2], cinh[2], cinl[2], hnh[2], hnl[2];
        split8(m_r,      mrh[0],  mrl[0]);  split8(m_r + 8,  mrh[1],  mrl[1]);
        split8(m_z,      mzh[0],  mzl[0]);  split8(m_z + 8,  mzh[1],  mzl[1]);
        split8(c_in,     cinh[0], cinl[0]); split8(c_in + 8, cinh[1], cinl[1]);
        split8(wh_n,     hnh[0],  hnl[0]);  split8(wh_n + 8, hnh[1],  hnl[1]);
        s8v r0h[2], r0l[2], z0h[2], z0l[2];
        split8(wh_r, r0h[0], r0l[0]); split8(wh_r + 8, r0h[1], r0l[1]);
        split8(wh_z, z0h[0], z0l[0]); split8(wh_z + 8, z0h[1], z0l[1]);
        s8v owh[2], owl[2];
        {
            float ov[16];
            #pragma unroll
            for (int c = 0; c < 2; ++c)
                #pragma unroll
                for (int jj = 0; jj < 8; ++jj)
                    ov[c * 8 + jj] = outW_l[col][c * 32 + q * 8 + jj];
            split8(ov, owh[0], owl[0]); split8(ov + 8, owh[1], owl[1]);
        }

        float b_r = dbhh[u] + dbih[u];
        float b_z = dbhh[u + 64] + dbih[u + 64];
        float b_in = dbih[u + 128];
        const float b_hn = dbhh[u + 128];
        #pragma unroll
        for (int j = 0; j < 16; ++j) {
            float obj = outb[j];
            b_r  = fmaf(obj, wi_r[j], b_r);
            b_z  = fmaf(obj, wi_z[j], b_z);
            b_in = fmaf(obj, wi_n[j], b_in);
        }
        const float ob = outb[col];

        // ---- heads weights (verified R6 frag patterns; chunk = w) ----
        s8v w1mh, w1ml, w1ch, w1cl;
        if (q < 2) {
            load_bfrag(mW1 + (size_t)(w * 16 + col) * 16 + q * 8, w1mh, w1ml);
            load_bfrag(cW1 + (size_t)(w * 16 + col) * 16 + q * 8, w1ch, w1cl);
        } else { w1mh = z8; w1ml = z8; w1ch = z8; w1cl = z8; }
        const float b1m = mb1[w * 16 + col];
        const float b1c = cb1[w * 16 + col];
        // stage2: wave 2 = mean head, wave 3 = cov head
        s8v w2h[2], w2l[2];
        w2h[0] = z8; w2l[0] = z8; w2h[1] = z8; w2l[1] = z8;
        float b2 = 0.0f;
        if (w == 2) {
            if (col < 4) {
                load_bfrag(mW2 + (size_t)col * 64 + q * 8,      w2h[0], w2l[0]);
                load_bfrag(mW2 + (size_t)col * 64 + 32 + q * 8, w2h[1], w2l[1]);
                b2 = mb2[col];
            }
        } else if (w == 3) {
            if (col < 10) {
                load_bfrag(cW2 + (size_t)col * 64 + q * 8,      w2h[0], w2l[0]);
                load_bfrag(cW2 + (size_t)col * 64 + 32 + q * 8, w2h[1], w2l[1]);
                b2 = cb2[col];
            }
        }

        float* means = out;
        float* covs  = out + MEANS_N;

        // coalesced chunk flush (R8): nsteps is a literal at both call
        // sites so the divisions const-fold after inlining.
        auto flush_out = [&](int s0, int nsteps) {
            const int buf = (s0 >> 4) & 1;
            for (int i = tid; i < 8 * nsteps * 4; i += 256) {
                int b = i / (nsteps * 4);
                int r = i - b * (nsteps * 4);
                means[(size_t)(b0 + b) * (SEQLEN * 4) + s0 * 4 + r] =
                    om_st[buf][b][r >> 2][r & 3];
            }
            for (int i = tid; i < 8 * nsteps * 10; i += 256) {
                int b = i / (nsteps * 10);
                int r = i - b * (nsteps * 10);
                covs[(size_t)(b0 + b) * (SEQLEN * 10) + s0 * 10 + r] =
                    cv_st[buf][b][r / 10][r % 10];
            }
        };

        float g_r[2], g_z[2], g_n[2];
        #pragma unroll
        for (int j2 = 0; j2 < 2; ++j2) {
            int row = rj0 + j2;
            float sr = dbih[u] + dbhh[u];
            float sz = dbih[u + 64] + dbhh[u + 64];
            float sn = dbih[u + 128];
            #pragma unroll
            for (int j = 0; j < 16; ++j) {
                float iv = init_l[row][j];
                sr = fmaf(wi_r[j], iv, sr);
                sz = fmaf(wi_z[j], iv, sz);
                sn = fmaf(wi_n[j], iv, sn);
            }
            g_r[j2] = sr; g_z[j2] = sz; g_n[j2] = sn;
        }

        // ---- dec step 0: h1 = GRU(h0, init_in); h0 already in buf0 ----
        {
            const s8v ah0 = *(const s8v*)&hiL[0][col][q * 8];
            const s8v al0 = *(const s8v*)&loL[0][col][q * 8];
            const s8v ah1 = *(const s8v*)&hiL[0][col][32 + q * 8];
            const s8v al1 = *(const s8v*)&loL[0][col][32 + q * 8];
            f4v ar, az, ahn;
            ar  = MFMA16(ah0, r0h[0], z4);
            az  = MFMA16(ah0, z0h[0], z4);
            ahn = MFMA16(ah0, hnh[0], z4);
            ar  = MFMA16(ah0, r0l[0], ar);
            az  = MFMA16(ah0, z0l[0], az);
            ahn = MFMA16(ah0, hnl[0], ahn);
            ar  = MFMA16(al0, r0h[0], ar);
            az  = MFMA16(al0, z0h[0], az);
            ahn = MFMA16(al0, hnh[0], ahn);
            ar  = MFMA16(ah1, r0h[1], ar);
            az  = MFMA16(ah1, z0h[1], az);
            ahn = MFMA16(ah1, hnh[1], ahn);
            ar  = MFMA16(ah1, r0l[1], ar);
            az  = MFMA16(ah1, z0l[1], az);
            ahn = MFMA16(ah1, hnl[1], ahn);
            ar  = MFMA16(al1, r0h[1], ar);
            az  = MFMA16(al1, z0h[1], az);
            ahn = MFMA16(al1, hnh[1], ahn);

            float pr[2], pz[2], pnh[2];
            pr[0]  = half_merge(ar[0],  ar[2]);
            pr[1]  = half_merge(ar[1],  ar[3]);
            pz[0]  = half_merge(az[0],  az[2]);
            pz[1]  = half_merge(az[1],  az[3]);
            pnh[0] = half_merge(ahn[0], ahn[2]);
            pnh[1] = half_merge(ahn[1], ahn[3]);

            #pragma unroll
            for (int j = 0; j < 2; ++j) {
                float r  = sigmoidf_(pr[j] + g_r[j]);
                float zz = sigmoidf_(pz[j] + g_z[j]);
                float n  = tanhf_(g_n[j] + r * (pnh[j] + b_hn));
                float h  = (1.0f - zz) * n + zz * hold2[j];
                hold2[j] = h;
                unsigned short hh = f2bf(h);
                hiL[1][rj0 + j][u] = hh;
                loL[1][rj0 + j][u] = f2bf(h - bf2f(hh));
            }
            __syncthreads();
        }

        // ---- pipelined dec steps t=1..SEQLEN+2 ----
        // t<=100: o_{t-1} -> o_sl[t&1];  t<=99: GRU update
        // t>=2:   stage1 on o_sl[(t-1)&1] -> H[t&1]
        // t>=3:   stage2 on H[(t-1)&1] -> staging chunk (step t-3)
        // flush:  step chunk [s0, s0+15] once stage2 writes are visible
        for (int t = 1; t <= SEQLEN + 2; ++t) {
            const int dcur = t & 1;

            {   // chunk flush: stage2 of step t-4 visible since last barrier
                const int sdone = t - 4;
                if (sdone >= 15 && (sdone & 15) == 15)
                    flush_out(sdone - 15, 16);
            }

            if (t <= SEQLEN) {
                const s8v ah0 = *(const s8v*)&hiL[dcur][col][q * 8];
                const s8v al0 = *(const s8v*)&loL[dcur][col][q * 8];
                const s8v ah1 = *(const s8v*)&hiL[dcur][col][32 + q * 8];
                const s8v al1 = *(const s8v*)&loL[dcur][col][32 + q * 8];

                if (w == ((t - 1) & 3)) {   // o_{t-1} -> LDS
                    f4v oa;
                    oa = MFMA16(ah0, owh[0], z4);
                    oa = MFMA16(ah0, owl[0], oa);
                    oa = MFMA16(al0, owh[0], oa);
                    oa = MFMA16(ah1, owh[1], oa);
                    oa = MFMA16(ah1, owl[1], oa);
                    oa = MFMA16(al1, owh[1], oa);
                    if (q < 2) {
                        #pragma unroll
                        for (int i = 0; i < 4; ++i)
                            o_sl[dcur][q * 4 + i][col] = oa[i] + ob;
                    }
                }

                if (t < SEQLEN) {           // GRU update (t=1..99)
                    f4v ar, az, ain, ahn;
                    ar  = MFMA16(ah0, mrh[0], z4);
                    az  = MFMA16(ah0, mzh[0], z4);
                    ain = MFMA16(ah0, cinh[0], z4);
                    ahn = MFMA16(ah0, hnh[0], z4);
                    ar  = MFMA16(ah0, mrl[0], ar);
                    az  = MFMA16(ah0, mzl[0], az);
                    ain = MFMA16(ah0, cinl[0], ain);
                    ahn = MFMA16(ah0, hnl[0], ahn);
                    ar  = MFMA16(al0, mrh[0], ar);
                    az  = MFMA16(al0, mzh[0], az);
                    ain = MFMA16(al0, cinh[0], ain);
                    ahn = MFMA16(al0, hnh[0], ahn);
                    ar  = MFMA16(ah1, mrh[1], ar);
                    az  = MFMA16(ah1, mzh[1], az);
                    ain = MFMA16(ah1, cinh[1], ain);
                    ahn = MFMA16(ah1, hnh[1], ahn);
                    ar  = MFMA16(ah1, mrl[1], ar);
                    az  = MFMA16(ah1, mzl[1], az);
                    ain = MFMA16(ah1, cinl[1], ain);
                    ahn = MFMA16(ah1, hnl[1], ahn);
                    ar  = MFMA16(al1, mrh[1], ar);
                    az  = MFMA16(al1, mzh[1], az);
                    ain = MFMA16(al1, cinh[1], ain);
                    ahn = MFMA16(al1, hnh[1], ahn);

                    float pr[2], pz[2], pin[2], pnh[2];
                    pr[0]  = half_merge(ar[0],  ar[2]);
                    pr[1]  = half_merge(ar[1],  ar[3]);
                    pz[0]  = half_merge(az[0],  az[2]);
                    pz[1]  = half_merge(az[1],  az[3]);
                    pin[0] = half_merge(ain[0], ain[2]);
                    pin[1] = half_merge(ain[1], ain[3]);
                    pnh[0] = half_merge(ahn[0], ahn[2]);
                    pnh[1] = half_merge(ahn[1], ahn[3]);

                    const int nxt = dcur ^ 1;
                    #pragma unroll
                    for (int j = 0; j < 2; ++j) {
                        float r  = sigmoidf_(pr[j] + b_r);
                        float zz = sigmoidf_(pz[j] + b_z);
                        float n  = tanhf_(pin[j] + b_in + r * (pnh[j] + b_hn));
                        float h  = (1.0f - zz) * n + zz * hold2[j];
                        hold2[j] = h;
                        unsigned short hh = f2bf(h);
                        hiL[nxt][rj0 + j][u] = hh;
                        loL[nxt][rj0 + j][u] = f2bf(h - bf2f(hh));
                    }
                }
            }

            if (t >= 2) {   // stage1 on o_{t-2} (all waves; chunk = w)
                const int po = (t - 1) & 1;
                const int ph = t & 1;
                s8v aoh, aol;
                if (q < 2 && col < 8) {
                    float4 a = *(const float4*)&o_sl[po][col][q * 8];
                    float4 b = *(const float4*)&o_sl[po][col][q * 8 + 4];
                    split2(a, b, aoh, aol);
                } else { aoh = z8; aol = z8; }

                f4v am = MFMA16(aoh, w1mh, z4);
                am = MFMA16(aoh, w1ml, am);
                am = MFMA16(aol, w1mh, am);
                f4v ac = MFMA16(aoh, w1ch, z4);
                ac = MFMA16(aoh, w1cl, ac);
                ac = MFMA16(aol, w1ch, ac);

                if (q < 2) {
                    #pragma unroll
                    for (int i = 0; i < 4; ++i) {
                        float hm = gelu_fast(am[i] + b1m);
                        unsigned short hh = f2bf(hm);
                        Hm_hi[ph][q * 4 + i][w * 16 + col] = hh;
                        Hm_lo[ph][q * 4 + i][w * 16 + col] = f2bf(hm - bf2f(hh));
                        float hc = gelu_fast(ac[i] + b1c);
                        hh = f2bf(hc);
                        Hc_hi[ph][q * 4 + i][w * 16 + col] = hh;
                        Hc_lo[ph][q * 4 + i][w * 16 + col] = f2bf(hc - bf2f(hh));
                    }
                }
            }

            if (t >= 3 && w >= 2) {   // stage2 on o_{t-3}: w2=mean, w3=cov
                const int ph2 = (t - 1) & 1;
                const int step = t - 3;
                s8v a0h, a0l, a1h, a1l;
                if (col < 8) {
                    if (w == 2) {
                        a0h = *(const s8v*)&Hm_hi[ph2][col][q * 8];
                        a0l = *(const s8v*)&Hm_lo[ph2][col][q * 8];
                        a1h = *(const s8v*)&Hm_hi[ph2][col][32 + q * 8];
                        a1l = *(const s8v*)&Hm_lo[ph2][col][32 + q * 8];
                    } else {
                        a0h = *(const s8v*)&Hc_hi[ph2][col][q * 8];
                        a0l = *(const s8v*)&Hc_lo[ph2][col][q * 8];
                        a1h = *(const s8v*)&Hc_hi[ph2][col][32 + q * 8];
                        a1l = *(const s8v*)&Hc_lo[ph2][col][32 + q * 8];
                    }
                } else { a0h = z8; a0l = z8; a1h = z8; a1l = z8; }

                f4v o2;
                o2 = MFMA16(a0h, w2h[0], z4);
                o2 = MFMA16(a0h, w2l[0], o2);
                o2 = MFMA16(a0l, w2h[0], o2);
                o2 = MFMA16(a1h, w2h[1], o2);
                o2 = MFMA16(a1h, w2l[1], o2);
                o2 = MFMA16(a1l, w2h[1], o2);

                const int sbuf = (step >> 4) & 1;
                const int sc   = step & 15;
                if (q < 2) {
                    if (w == 2) {
                        if (col < 4) {
                            #pragma unroll
                            for (int i = 0; i < 4; ++i) {
                                float v = o2[i] + b2;
                                if (col >= 2) v = fminf(fmaxf(v, -1.0f), 1.0f);
                                om_st[sbuf][q * 4 + i][sc][col] = v;
                            }
                        }
                    } else {
                        if (col < 10) {
                            #pragma unroll
                            for (int i = 0; i < 4; ++i)
                                cv_st[sbuf][q * 4 + i][sc][col] = o2[i] + b2;
                        }
                    }
                }
            }

            __syncthreads();
        }

        // ---- final flush: steps 96..99 (visible after loop's last barrier) ----
        flush_out(96, 4);
    }
}

// =====================================================================
extern "C" void kernel_launch(void* const* d_in, const int* in_sizes, int n_in,
                              void* d_out, int out_size, void* d_ws, size_t ws_size,
                              hipStream_t stream)
{
    const float* x    = (const float*)d_in[0];
    const float* trg  = (const float*)d_in[1];
    const float* eWih = (const float*)d_in[2];
    const float* ebih = (const float*)d_in[3];
    const float* eWhh = (const float*)d_in[4];
    const float* ebhh = (const float*)d_in[5];
    const float* dWih = (const float*)d_in[6];
    const float* dbih = (const float*)d_in[7];
    const float* dWhh = (const float*)d_in[8];
    const float* dbhh = (const float*)d_in[9];
    const float* outW = (const float*)d_in[10];
    const float* outb = (const float*)d_in[11];
    const float* embW = (const float*)d_in[12];
    const float* embb = (const float*)d_in[13];
    const float* mW1  = (const float*)d_in[14];
    const float* mb1  = (const float*)d_in[15];
    const float* mW2  = (const float*)d_in[16];
    const float* mb2  = (const float*)d_in[17];
    const float* cW1  = (const float*)d_in[18];
    const float* cb1  = (const float*)d_in[19];
    const float* cW2  = (const float*)d_in[20];
    const float* cb2  = (const float*)d_in[21];

    float* outp = (float*)d_out;

    fused_gru_kernel<<<dim3(BTOT / 8), dim3(256), 0, stream>>>(
        x, eWih, ebih, eWhh, ebhh, dWih, dbih, dWhh, dbhh,
        outW, outb, embW, embb, trg,
        mW1, mb1, mW2, mb2, cW1, cb1, cW2, cb2, outp);
}

// Round 9
// 359.540 us; speedup vs baseline: 1.3424x; 1.3424x over previous
//
#include <hip/hip_runtime.h>
#include <cstdint>
#include <cstddef>

// Problem constants (match reference)
#define BTOT    4096
#define SRCLEN  128
#define INDIM   16
#define HDIM    64
#define SEQLEN  100
#define MEANS_N (BTOT * SEQLEN * 4)   // 1638400

// ---------- helpers ----------
__device__ __forceinline__ float sigmoidf_(float x) {
    return __builtin_amdgcn_rcpf(1.0f + __expf(-x));
}
__device__ __forceinline__ float tanhf_(float x) {
    float e = __expf(2.0f * x);
    return 1.0f - 2.0f * __builtin_amdgcn_rcpf(e + 1.0f);
}
// gelu via Abramowitz-Stegun 7.1.26 erf (|err| < 1.5e-7)
__device__ __forceinline__ float gelu_fast(float x) {
    float z = fabsf(x) * 0.70710678118654752440f;
    float t = __builtin_amdgcn_rcpf(1.0f + 0.3275911f * z);
    float p = t * (0.254829592f +
              t * (-0.284496736f +
              t * (1.421413741f +
              t * (-1.453152027f +
              t * 1.061405429f))));
    float er = 1.0f - p * __expf(-z * z);
    er = copysignf(er, x);
    return 0.5f * x * (1.0f + er);
}

// ---------- bf16 split helpers (bf16x3 emulated-fp32 MFMA) ----------
typedef __attribute__((ext_vector_type(8))) short s8v;   // 8 bf16 (4 VGPRs)
typedef __attribute__((ext_vector_type(4))) float f4v;   // 4 fp32
typedef unsigned short ush;

__device__ __forceinline__ ush f2bf(float x) {  // RTNE float -> bf16 bits
    unsigned u = __float_as_uint(x);
    unsigned r = (u + 0x7FFFu + ((u >> 16) & 1u)) >> 16;
    return (ush)r;
}
__device__ __forceinline__ float bf2f(ush b) {
    return __uint_as_float(((unsigned)b) << 16);
}
__device__ __forceinline__ void split2(float4 a, float4 b, s8v& hi, s8v& lo) {
    float v[8] = {a.x, a.y, a.z, a.w, b.x, b.y, b.z, b.w};
    #pragma unroll
    for (int j = 0; j < 8; ++j) {
        ush h = f2bf(v[j]);
        hi[j] = (short)h;
        lo[j] = (short)f2bf(v[j] - bf2f(h));
    }
}
__device__ __forceinline__ void split8(const float* v, s8v& hi, s8v& lo) {
    #pragma unroll
    for (int j = 0; j < 8; ++j) {
        ush h = f2bf(v[j]);
        hi[j] = (short)h;
        lo[j] = (short)f2bf(v[j] - bf2f(h));
    }
}
__device__ __forceinline__ void load_bfrag(const float* p, s8v& hi, s8v& lo) {
    float4 a = *(const float4*)p;
    float4 b = *(const float4*)(p + 4);
    split2(a, b, hi, lo);
}

// permlane32_swap merge: lanes 0-31 keep own_lo, lanes 32-63 get send_hi
typedef __attribute__((ext_vector_type(2))) unsigned int u2v;
__device__ __forceinline__ float half_merge(float own_lo, float send_hi) {
    u2v r = __builtin_amdgcn_permlane32_swap(__float_as_uint(own_lo),
                                             __float_as_uint(send_hi),
                                             false, false);
    return __uint_as_float(r[0]);
}

#define MFMA16(a, b, c) __builtin_amdgcn_mfma_f32_16x16x32_bf16((a), (b), (c), 0, 0, 0)

// =====================================================================
// FULLY FUSED enc + dec + heads, SEQUENTIAL phases (R9).
// R7/R8's interleaved pipeline spilled (phantom ~150MB write / ~60MB
// fetch = scratch traffic; staging fix didn't move it). R9 keeps the
// verified R6 phases but strictly sequential so register liveness is
// disjoint:
//   phase 1: enc (R6-exact)
//   phase 2: dec (R6-exact) with o-tiles -> LDS o_all[800][20]
//            (aliases the dead enc x-buffers; 8 batches x 100 steps fp32)
//   phase 3: heads, 50 tiles x 16 rows; stage1 per-wave c-chunk=w,
//            stage2 wave2=mean / wave3=cov (R7-verified lane patterns);
//            H transpose buffers alias the dead hiL/loL region (9216 B).
// LDS total 77824 B -> 2 blocks/CU. No dec_o HBM round-trip, 1 launch.
// =====================================================================
__global__ __launch_bounds__(256, 2) void fused_all_kernel(
    const float* __restrict__ x,
    const float* __restrict__ eWih, const float* __restrict__ ebih,
    const float* __restrict__ eWhh, const float* __restrict__ ebhh,
    const float* __restrict__ dWih, const float* __restrict__ dbih,
    const float* __restrict__ dWhh, const float* __restrict__ dbhh,
    const float* __restrict__ outW, const float* __restrict__ outb,
    const float* __restrict__ embW, const float* __restrict__ embb,
    const float* __restrict__ trg,
    const float* __restrict__ mW1, const float* __restrict__ mb1,
    const float* __restrict__ mW2, const float* __restrict__ mb2,
    const float* __restrict__ cW1, const float* __restrict__ cb1,
    const float* __restrict__ cW2, const float* __restrict__ cb2,
    float* __restrict__ out)
{
    const int tid  = threadIdx.x;
    const int lane = tid & 63;
    const int w    = tid >> 6;     // wave 0..3
    const int col  = lane & 15;
    const int q    = lane >> 4;
    const int u    = w * 16 + col;
    const int b0   = blockIdx.x * 8;
    // post-rebalance batch row for item j: rows {0,1},{4,5},{2,3},{6,7} for q=0..3
    const int rj0  = (q & 1) * 4 + ((q >> 1) << 1);

    // ---- aliased LDS regions ----
    __shared__ __align__(16) char regA_c[9216];    // hiL+loL  | phase3 H bufs
    __shared__ __align__(16) char regB_c[64000];   // enc x    | o_all[800][20]
    __shared__ __align__(16) float outW_l[16][64];
    __shared__ float init_l[8][16];

    ush (*hiL)[16][72] = (ush(*)[16][72])regA_c;            // [2][16][72]
    ush (*loL)[16][72] = (ush(*)[16][72])(regA_c + 4608);
    ush (*xhi_l)[9][16] = (ush(*)[9][16])regB_c;            // [64][9][16]
    ush (*xlo_l)[9][16] = (ush(*)[9][16])(regB_c + 18432);
    float (*o_all)[20] = (float(*)[20])regB_c;              // [800][20]
    // phase-3 H buffers (valid only after dec loop; alias hiL/loL)
    ush (*Hm_hi)[72] = (ush(*)[72])regA_c;                  // [16][72]
    ush (*Hm_lo)[72] = (ush(*)[72])(regA_c + 2304);
    ush (*Hc_hi)[72] = (ush(*)[72])(regA_c + 4608);
    ush (*Hc_lo)[72] = (ush(*)[72])(regA_c + 6912);

    // ---- stage dec LDS (outW, init_in) ----
    for (int i = tid; i < 16 * 64; i += 256) outW_l[i >> 6][i & 63] = outW[i];
    if (tid < 128) {
        int b = tid >> 4, jj = tid & 15;
        float s = embb[jj];
        #pragma unroll
        for (int s4 = 0; s4 < 4; ++s4)
            s = fmaf(embW[jj * 4 + s4], trg[(size_t)(b0 + b) * 4 + s4], s);
        init_l[b][jj] = s;
    }

    // ---- enc init: zero both h buffers (rows 8-15 stay zero forever) ----
    for (int i = tid; i < 4608; i += 256) ((ush*)regA_c)[i] = 0;
    for (int i = tid; i < 64 * 16; i += 256) {
        xhi_l[i >> 4][8][i & 15] = 0;
        xlo_l[i >> 4][8][i & 15] = 0;
    }

    // stage one 64-step chunk of x, pre-split into bf16 hi/lo
    auto stage_x = [&](int c) {
        #pragma unroll
        for (int k = 0; k < 8; ++k) {
            int f   = tid + k * 256;
            int b   = f >> 8;
            int rem = f & 255;
            int tl  = rem >> 2;
            int d4  = (rem & 3) << 2;
            const float* xp = x + ((size_t)(b0 + b) * SRCLEN + (c * 64 + tl)) * INDIM + d4;
            float4 v = *(const float4*)xp;
            float vv[4] = {v.x, v.y, v.z, v.w};
            ush hh[4], ll[4];
            #pragma unroll
            for (int j = 0; j < 4; ++j) {
                hh[j] = f2bf(vv[j]);
                ll[j] = f2bf(vv[j] - bf2f(hh[j]));
            }
            *(ushort4*)&xhi_l[tl][b][d4] = make_ushort4(hh[0], hh[1], hh[2], hh[3]);
            *(ushort4*)&xlo_l[tl][b][d4] = make_ushort4(ll[0], ll[1], ll[2], ll[3]);
        }
    };

    const s8v z8 = {0, 0, 0, 0, 0, 0, 0, 0};
    const f4v z4 = {0.0f, 0.0f, 0.0f, 0.0f};

    // ================= PHASE 1: ENCODER (R6-exact) =================
    float hold2e[2];
    {
        s8v brh[3], brl[3], bzh[3], bzl[3], bnhh[2], bnhl[2], bnxh, bnxl;
        load_bfrag(eWhh + (size_t)u * 64 + q * 8,              brh[0], brl[0]);
        load_bfrag(eWhh + (size_t)u * 64 + 32 + q * 8,         brh[1], brl[1]);
        load_bfrag(eWhh + (size_t)(64 + u) * 64 + q * 8,       bzh[0], bzl[0]);
        load_bfrag(eWhh + (size_t)(64 + u) * 64 + 32 + q * 8,  bzh[1], bzl[1]);
        load_bfrag(eWhh + (size_t)(128 + u) * 64 + q * 8,      bnhh[0], bnhl[0]);
        load_bfrag(eWhh + (size_t)(128 + u) * 64 + 32 + q * 8, bnhh[1], bnhl[1]);
        if (q < 2) {
            load_bfrag(eWih + (size_t)u * 16 + q * 8,         brh[2], brl[2]);
            load_bfrag(eWih + (size_t)(64 + u) * 16 + q * 8,  bzh[2], bzl[2]);
            load_bfrag(eWih + (size_t)(128 + u) * 16 + q * 8, bnxh, bnxl);
        } else {
            brh[2] = z8; brl[2] = z8; bzh[2] = z8; bzl[2] = z8; bnxh = z8; bnxl = z8;
        }

        const float br   = ebih[u] + ebhh[u];
        const float bz   = ebih[u + 64] + ebhh[u + 64];
        const float bnx  = ebih[u + 128];
        const float bnh  = ebhh[u + 128];

        const int xb   = (q < 2) ? (col & 7) : 8;
        const int xoff = (q & 1) * 8;
        const ush* xh_base = &xhi_l[0][xb][xoff];
        const ush* xl_base = &xlo_l[0][xb][xoff];

        stage_x(0);
        hold2e[0] = 0.0f; hold2e[1] = 0.0f;
        __syncthreads();

        int cur = 0;
        for (int t = 0; t < SRCLEN; ++t) {
            if (t == 64) {
                stage_x(1);
                __syncthreads();
            }
            const int tl = t & 63;

            const s8v xh = *(const s8v*)(xh_base + (size_t)tl * 144);
            const s8v xl = *(const s8v*)(xl_base + (size_t)tl * 144);

            const s8v ah0 = *(const s8v*)&hiL[cur][col][q * 8];
            const s8v al0 = *(const s8v*)&loL[cur][col][q * 8];
            const s8v ah1 = *(const s8v*)&hiL[cur][col][32 + q * 8];
            const s8v al1 = *(const s8v*)&loL[cur][col][32 + q * 8];

            f4v accr, accz, accnh, accnx;
            accr  = MFMA16(ah0, brh[0], z4);
            accz  = MFMA16(ah0, bzh[0], z4);
            accnh = MFMA16(ah0, bnhh[0], z4);
            accr  = MFMA16(ah0, brl[0], accr);
            accz  = MFMA16(ah0, bzl[0], accz);
            accnh = MFMA16(ah0, bnhl[0], accnh);
            accr  = MFMA16(al0, brh[0], accr);
            accz  = MFMA16(al0, bzh[0], accz);
            accnh = MFMA16(al0, bnhh[0], accnh);
            accr  = MFMA16(ah1, brh[1], accr);
            accz  = MFMA16(ah1, bzh[1], accz);
            accnh = MFMA16(ah1, bnhh[1], accnh);
            accr  = MFMA16(ah1, brl[1], accr);
            accz  = MFMA16(ah1, bzl[1], accz);
            accnh = MFMA16(ah1, bnhl[1], accnh);
            accr  = MFMA16(al1, brh[1], accr);
            accz  = MFMA16(al1, bzh[1], accz);
            accnh = MFMA16(al1, bnhh[1], accnh);
            accr  = MFMA16(xh, brh[2], accr);
            accz  = MFMA16(xh, bzh[2], accz);
            accnx = MFMA16(xh, bnxh, z4);
            accr  = MFMA16(xh, brl[2], accr);
            accz  = MFMA16(xh, bzl[2], accz);
            accnx = MFMA16(xh, bnxl, accnx);
            accr  = MFMA16(xl, brh[2], accr);
            accz  = MFMA16(xl, bzh[2], accz);
            accnx = MFMA16(xl, bnxh, accnx);

            float pr[2], pz[2], pnh[2], pnx[2];
            pr[0]  = half_merge(accr[0],  accr[2]);
            pr[1]  = half_merge(accr[1],  accr[3]);
            pz[0]  = half_merge(accz[0],  accz[2]);
            pz[1]  = half_merge(accz[1],  accz[3]);
            pnh[0] = half_merge(accnh[0], accnh[2]);
            pnh[1] = half_merge(accnh[1], accnh[3]);
            pnx[0] = half_merge(accnx[0], accnx[2]);
            pnx[1] = half_merge(accnx[1], accnx[3]);

            const int nxt = cur ^ 1;
            #pragma unroll
            for (int j = 0; j < 2; ++j) {
                float r  = sigmoidf_(pr[j] + br);
                float zz = sigmoidf_(pz[j] + bz);
                float n  = tanhf_(pnx[j] + bnx + r * (pnh[j] + bnh));
                float h  = (1.0f - zz) * n + zz * hold2e[j];
                hold2e[j] = h;
                ush hh = f2bf(h);
                hiL[nxt][rj0 + j][u] = hh;
                loL[nxt][rj0 + j][u] = f2bf(h - bf2f(hh));
            }
            __syncthreads();
            cur ^= 1;
        }
    }

    // ================= PHASE 2: DECODER (R6-exact; o -> LDS) =========
    {
        float hold2[2] = {hold2e[0], hold2e[1]};

        float wh_r[16], wh_z[16], wh_n[16];
        #pragma unroll
        for (int c = 0; c < 2; ++c)
            #pragma unroll
            for (int jj = 0; jj < 8; ++jj) {
                int k = c * 32 + q * 8 + jj;
                wh_r[c * 8 + jj] = dWhh[(size_t)u * 64 + k];
                wh_z[c * 8 + jj] = dWhh[(size_t)(64 + u) * 64 + k];
                wh_n[c * 8 + jj] = dWhh[(size_t)(128 + u) * 64 + k];
            }
        float wi_r[16], wi_z[16], wi_n[16];
        #pragma unroll
        for (int j = 0; j < 16; ++j) {
            wi_r[j] = dWih[(size_t)u * 16 + j];
            wi_z[j] = dWih[(size_t)(64 + u) * 16 + j];
            wi_n[j] = dWih[(size_t)(128 + u) * 16 + j];
        }

        float m_r[16], m_z[16], c_in[16];
        #pragma unroll
        for (int c = 0; c < 2; ++c)
            #pragma unroll
            for (int jj = 0; jj < 8; ++jj) {
                int k = c * 32 + q * 8 + jj;
                float sr = 0.0f, sz = 0.0f, sn = 0.0f;
                #pragma unroll
                for (int j = 0; j < 16; ++j) {
                    float ow = outW_l[j][k];
                    sr = fmaf(wi_r[j], ow, sr);
                    sz = fmaf(wi_z[j], ow, sz);
                    sn = fmaf(wi_n[j], ow, sn);
                }
                m_r[c * 8 + jj]  = wh_r[c * 8 + jj] + sr;
                m_z[c * 8 + jj]  = wh_z[c * 8 + jj] + sz;
                c_in[c * 8 + jj] = sn;
            }

        s8v mrh[2], mrl[2], mzh[2], mzl[2], cinh[2], cinl[2], hnh[2], hnl[2];
        split8(m_r,      mrh[0],  mrl[0]);  split8(m_r + 8,  mrh[1],  mrl[1]);
        split8(m_z,      mzh[0],  mzl[0]);  split8(m_z + 8,  mzh[1],  mzl[1]);
        split8(c_in,     cinh[0], cinl[0]); split8(c_in + 8, cinh[1], cinl[1]);
        split8(wh_n,     hnh[0],  hnl[0]);  split8(wh_n + 8, hnh[1],  hnl[1]);
        s8v r0h[2], r0l[2], z0h[2], z0l[2];
        split8(wh_r, r0h[0], r0l[0]); split8(wh_r + 8, r0h[1], r0l[1]);
        split8(wh_z, z0h[0], z0l[0]); split8(wh_z + 8, z0h[1], z0l[1]);
        s8v owh[2], owl[2];
        {
            float ov[16];
            #pragma unroll
            for (int c = 0; c < 2; ++c)
                #pragma unroll
                for (int jj = 0; jj < 8; ++jj)
                    ov[c * 8 + jj] = outW_l[col][c * 32 + q * 8 + jj];
            split8(ov, owh[0], owl[0]); split8(ov + 8, owh[1], owl[1]);
        }

        float b_r = dbhh[u] + dbih[u];
        float b_z = dbhh[u + 64] + dbih[u + 64];
        float b_in = dbih[u + 128];
        const float b_hn = dbhh[u + 128];
        #pragma unroll
        for (int j = 0; j < 16; ++j) {
            float obj = outb[j];
            b_r  = fmaf(obj, wi_r[j], b_r);
            b_z  = fmaf(obj, wi_z[j], b_z);
            b_in = fmaf(obj, wi_n[j], b_in);
        }
        const float ob = outb[col];

        float g_r[2], g_z[2], g_n[2];
        #pragma unroll
        for (int j2 = 0; j2 < 2; ++j2) {
            int row = rj0 + j2;
            float sr = dbih[u] + dbhh[u];
            float sz = dbih[u + 64] + dbhh[u + 64];
            float sn = dbih[u + 128];
            #pragma unroll
            for (int j = 0; j < 16; ++j) {
                float iv = init_l[row][j];
                sr = fmaf(wi_r[j], iv, sr);
                sz = fmaf(wi_z[j], iv, sz);
                sn = fmaf(wi_n[j], iv, sn);
            }
            g_r[j2] = sr; g_z[j2] = sz; g_n[j2] = sn;
        }

        // ---- dec step 0: h1 = GRU(h0, init_in); h0 already in buf0 ----
        {
            const s8v ah0 = *(const s8v*)&hiL[0][col][q * 8];
            const s8v al0 = *(const s8v*)&loL[0][col][q * 8];
            const s8v ah1 = *(const s8v*)&hiL[0][col][32 + q * 8];
            const s8v al1 = *(const s8v*)&loL[0][col][32 + q * 8];
            f4v ar, az, ahn;
            ar  = MFMA16(ah0, r0h[0], z4);
            az  = MFMA16(ah0, z0h[0], z4);
            ahn = MFMA16(ah0, hnh[0], z4);
            ar  = MFMA16(ah0, r0l[0], ar);
            az  = MFMA16(ah0, z0l[0], az);
            ahn = MFMA16(ah0, hnl[0], ahn);
            ar  = MFMA16(al0, r0h[0], ar);
            az  = MFMA16(al0, z0h[0], az);
            ahn = MFMA16(al0, hnh[0], ahn);
            ar  = MFMA16(ah1, r0h[1], ar);
            az  = MFMA16(ah1, z0h[1], az);
            ahn = MFMA16(ah1, hnh[1], ahn);
            ar  = MFMA16(ah1, r0l[1], ar);
            az  = MFMA16(ah1, z0l[1], az);
            ahn = MFMA16(ah1, hnl[1], ahn);
            ar  = MFMA16(al1, r0h[1], ar);
            az  = MFMA16(al1, z0h[1], az);
            ahn = MFMA16(al1, hnh[1], ahn);

            float pr[2], pz[2], pnh[2];
            pr[0]  = half_merge(ar[0],  ar[2]);
            pr[1]  = half_merge(ar[1],  ar[3]);
            pz[0]  = half_merge(az[0],  az[2]);
            pz[1]  = half_merge(az[1],  az[3]);
            pnh[0] = half_merge(ahn[0], ahn[2]);
            pnh[1] = half_merge(ahn[1], ahn[3]);

            #pragma unroll
            for (int j = 0; j < 2; ++j) {
                float r  = sigmoidf_(pr[j] + g_r[j]);
                float zz = sigmoidf_(pz[j] + g_z[j]);
                float n  = tanhf_(g_n[j] + r * (pnh[j] + b_hn));
                float h  = (1.0f - zz) * n + zz * hold2[j];
                hold2[j] = h;
                ush hh = f2bf(h);
                hiL[1][rj0 + j][u] = hh;
                loL[1][rj0 + j][u] = f2bf(h - bf2f(hh));
            }
            __syncthreads();
        }

        // ---- dec steps 1..99; o_{t-1} (round-robin wave) -> o_all ----
        for (int t = 1; t < SEQLEN; ++t) {
            const int dcur = t & 1;
            const s8v ah0 = *(const s8v*)&hiL[dcur][col][q * 8];
            const s8v al0 = *(const s8v*)&loL[dcur][col][q * 8];
            const s8v ah1 = *(const s8v*)&hiL[dcur][col][32 + q * 8];
            const s8v al1 = *(const s8v*)&loL[dcur][col][32 + q * 8];

            if (w == ((t - 1) & 3)) {
                f4v oa;
                oa = MFMA16(ah0, owh[0], z4);
                oa = MFMA16(ah0, owl[0], oa);
                oa = MFMA16(al0, owh[0], oa);
                oa = MFMA16(ah1, owh[1], oa);
                oa = MFMA16(ah1, owl[1], oa);
                oa = MFMA16(al1, owh[1], oa);
                if (q < 2) {
                    #pragma unroll
                    for (int i = 0; i < 4; ++i)
                        o_all[(q * 4 + i) * SEQLEN + (t - 1)][col] = oa[i] + ob;
                }
            }

            f4v ar, az, ain, ahn;
            ar  = MFMA16(ah0, mrh[0], z4);
            az  = MFMA16(ah0, mzh[0], z4);
            ain = MFMA16(ah0, cinh[0], z4);
            ahn = MFMA16(ah0, hnh[0], z4);
            ar  = MFMA16(ah0, mrl[0], ar);
            az  = MFMA16(ah0, mzl[0], az);
            ain = MFMA16(ah0, cinl[0], ain);
            ahn = MFMA16(ah0, hnl[0], ahn);
            ar  = MFMA16(al0, mrh[0], ar);
            az  = MFMA16(al0, mzh[0], az);
            ain = MFMA16(al0, cinh[0], ain);
            ahn = MFMA16(al0, hnh[0], ahn);
            ar  = MFMA16(ah1, mrh[1], ar);
            az  = MFMA16(ah1, mzh[1], az);
            ain = MFMA16(ah1, cinh[1], ain);
            ahn = MFMA16(ah1, hnh[1], ahn);
            ar  = MFMA16(ah1, mrl[1], ar);
            az  = MFMA16(ah1, mzl[1], az);
            ain = MFMA16(ah1, cinl[1], ain);
            ahn = MFMA16(ah1, hnl[1], ahn);
            ar  = MFMA16(al1, mrh[1], ar);
            az  = MFMA16(al1, mzh[1], az);
            ain = MFMA16(al1, cinh[1], ain);
            ahn = MFMA16(al1, hnh[1], ahn);

            float pr[2], pz[2], pin[2], pnh[2];
            pr[0]  = half_merge(ar[0],  ar[2]);
            pr[1]  = half_merge(ar[1],  ar[3]);
            pz[0]  = half_merge(az[0],  az[2]);
            pz[1]  = half_merge(az[1],  az[3]);
            pin[0] = half_merge(ain[0], ain[2]);
            pin[1] = half_merge(ain[1], ain[3]);
            pnh[0] = half_merge(ahn[0], ahn[2]);
            pnh[1] = half_merge(ahn[1], ahn[3]);

            const int nxt = dcur ^ 1;
            #pragma unroll
            for (int j = 0; j < 2; ++j) {
                float r  = sigmoidf_(pr[j] + b_r);
                float zz = sigmoidf_(pz[j] + b_z);
                float n  = tanhf_(pin[j] + b_in + r * (pnh[j] + b_hn));
                float h  = (1.0f - zz) * n + zz * hold2[j];
                hold2[j] = h;
                ush hh = f2bf(h);
                hiL[nxt][rj0 + j][u] = hh;
                loL[nxt][rj0 + j][u] = f2bf(h - bf2f(hh));
            }
            __syncthreads();
        }

        // ---- epilogue: o_99 = h_100 @ outW^T + outb (buf 0) ----
        if (w == 0) {
            const s8v ah0 = *(const s8v*)&hiL[0][col][q * 8];
            const s8v al0 = *(const s8v*)&loL[0][col][q * 8];
            const s8v ah1 = *(const s8v*)&hiL[0][col][32 + q * 8];
            const s8v al1 = *(const s8v*)&loL[0][col][32 + q * 8];
            f4v oa;
            oa = MFMA16(ah0, owh[0], z4);
            oa = MFMA16(ah0, owl[0], oa);
            oa = MFMA16(al0, owh[0], oa);
            oa = MFMA16(ah1, owh[1], oa);
            oa = MFMA16(ah1, owl[1], oa);
            oa = MFMA16(al1, owh[1], oa);
            if (q < 2) {
                #pragma unroll
                for (int i = 0; i < 4; ++i)
                    o_all[(q * 4 + i) * SEQLEN + (SEQLEN - 1)][col] = oa[i] + ob;
            }
        }
    }

    // keep phase-3 weight loads below the dec loop (no hoisting across)
    __builtin_amdgcn_sched_barrier(0);

    // ================= PHASE 3: HEADS (50 tiles x 16 rows) ===========
    {
        // stage1 weights: per-wave c-chunk = w (R7-verified pattern)
        s8v w1mh, w1ml, w1ch, w1cl;
        if (q < 2) {
            load_bfrag(mW1 + (size_t)(w * 16 + col) * 16 + q * 8, w1mh, w1ml);
            load_bfrag(cW1 + (size_t)(w * 16 + col) * 16 + q * 8, w1ch, w1cl);
        } else { w1mh = z8; w1ml = z8; w1ch = z8; w1cl = z8; }
        const float b1m = mb1[w * 16 + col];
        const float b1c = cb1[w * 16 + col];
        // stage2 weights: wave 2 = mean head, wave 3 = cov head
        s8v w2h[2], w2l[2];
        w2h[0] = z8; w2l[0] = z8; w2h[1] = z8; w2l[1] = z8;
        float b2 = 0.0f;
        if (w == 2) {
            if (col < 4) {
                load_bfrag(mW2 + (size_t)col * 64 + q * 8,      w2h[0], w2l[0]);
                load_bfrag(mW2 + (size_t)col * 64 + 32 + q * 8, w2h[1], w2l[1]);
                b2 = mb2[col];
            }
        } else if (w == 3) {
            if (col < 10) {
                load_bfrag(cW2 + (size_t)col * 64 + q * 8,      w2h[0], w2l[0]);
                load_bfrag(cW2 + (size_t)col * 64 + 32 + q * 8, w2h[1], w2l[1]);
                b2 = cb2[col];
            }
        }

        float* means = out;
        float* covs  = out + MEANS_N;

        __syncthreads();   // epilogue o-write + hiL last reads done -> H aliases OK

        #pragma unroll 1
        for (int tile = 0; tile < 50; ++tile) {
            const int r0 = tile * 16;

            // ---- stage1: A = o rows (K=16, q<2 real); H cols w*16.. ----
            s8v ah, al;
            if (q < 2) {
                load_bfrag(&o_all[r0 + col][q * 8], ah, al);
            } else { ah = z8; al = z8; }

            f4v am = MFMA16(ah, w1mh, z4);
            am = MFMA16(ah, w1ml, am);
            am = MFMA16(al, w1mh, am);
            f4v ac = MFMA16(ah, w1ch, z4);
            ac = MFMA16(ah, w1cl, ac);
            ac = MFMA16(al, w1ch, ac);

            #pragma unroll
            for (int i = 0; i < 4; ++i) {
                float hm = gelu_fast(am[i] + b1m);
                ush hh = f2bf(hm);
                Hm_hi[q * 4 + i][w * 16 + col] = hh;
                Hm_lo[q * 4 + i][w * 16 + col] = f2bf(hm - bf2f(hh));
                float hc = gelu_fast(ac[i] + b1c);
                hh = f2bf(hc);
                Hc_hi[q * 4 + i][w * 16 + col] = hh;
                Hc_lo[q * 4 + i][w * 16 + col] = f2bf(hc - bf2f(hh));
            }
            __syncthreads();

            // ---- stage2: out = H @ W2^T + b2 (w2=mean, w3=cov) ----
            if (w >= 2) {
                s8v a0h, a0l, a1h, a1l;
                if (w == 2) {
                    a0h = *(const s8v*)&Hm_hi[col][q * 8];
                    a0l = *(const s8v*)&Hm_lo[col][q * 8];
                    a1h = *(const s8v*)&Hm_hi[col][32 + q * 8];
                    a1l = *(const s8v*)&Hm_lo[col][32 + q * 8];
                } else {
                    a0h = *(const s8v*)&Hc_hi[col][q * 8];
                    a0l = *(const s8v*)&Hc_lo[col][q * 8];
                    a1h = *(const s8v*)&Hc_hi[col][32 + q * 8];
                    a1l = *(const s8v*)&Hc_lo[col][32 + q * 8];
                }

                f4v o2;
                o2 = MFMA16(a0h, w2h[0], z4);
                o2 = MFMA16(a0h, w2l[0], o2);
                o2 = MFMA16(a0l, w2h[0], o2);
                o2 = MFMA16(a1h, w2h[1], o2);
                o2 = MFMA16(a1h, w2l[1], o2);
                o2 = MFMA16(a1l, w2h[1], o2);

                if (w == 2) {
                    if (col < 4) {
                        #pragma unroll
                        for (int i = 0; i < 4; ++i) {
                            int r  = r0 + q * 4 + i;           // 0..799
                            int b  = (r * 41) >> 12;           // r / 100
                            int st = r - b * 100;
                            float v = o2[i] + b2;
                            if (col >= 2) v = fminf(fmaxf(v, -1.0f), 1.0f);
                            means[(size_t)(b0 + b) * (SEQLEN * 4) + st * 4 + col] = v;
                        }
                    }
                } else {
                    if (col < 10) {
                        #pragma unroll
                        for (int i = 0; i < 4; ++i) {
                            int r  = r0 + q * 4 + i;
                            int b  = (r * 41) >> 12;
                            int st = r - b * 100;
                            covs[(size_t)(b0 + b) * (SEQLEN * 10) + st * 10 + col] = o2[i] + b2;
                        }
                    }
                }
            }
            __syncthreads();   // H consumed -> next tile may overwrite
        }
    }
}

// =====================================================================
extern "C" void kernel_launch(void* const* d_in, const int* in_sizes, int n_in,
                              void* d_out, int out_size, void* d_ws, size_t ws_size,
                              hipStream_t stream)
{
    const float* x    = (const float*)d_in[0];
    const float* trg  = (const float*)d_in[1];
    const float* eWih = (const float*)d_in[2];
    const float* ebih = (const float*)d_in[3];
    const float* eWhh = (const float*)d_in[4];
    const float* ebhh = (const float*)d_in[5];
    const float* dWih = (const float*)d_in[6];
    const float* dbih = (const float*)d_in[7];
    const float* dWhh = (const float*)d_in[8];
    const float* dbhh = (const float*)d_in[9];
    const float* outW = (const float*)d_in[10];
    const float* outb = (const float*)d_in[11];
    const float* embW = (const float*)d_in[12];
    const float* embb = (const float*)d_in[13];
    const float* mW1  = (const float*)d_in[14];
    const float* mb1  = (const float*)d_in[15];
    const float* mW2  = (const float*)d_in[16];
    const float* mb2  = (const float*)d_in[17];
    const float* cW1  = (const float*)d_in[18];
    const float* cb1  = (const float*)d_in[19];
    const float* cW2  = (const float*)d_in[20];
    const float* cb2  = (const float*)d_in[21];

    float* outp = (float*)d_out;

    fused_all_kernel<<<dim3(BTOT / 8), dim3(256), 0, stream>>>(
        x, eWih, ebih, eWhh, ebhh, dWih, dbih, dWhh, dbhh,
        outW, outb, embW, embb, trg,
        mW1, mb1, mW2, mb2, cW1, cb1, cW2, cb2, outp);
}

// Round 10
// 353.269 us; speedup vs baseline: 1.3662x; 1.0178x over previous
//
#include <hip/hip_runtime.h>
#include <hip/hip_bf16.h>
#include <cstdint>
#include <cstddef>

// Problem constants (match reference)
#define BTOT    4096
#define SRCLEN  128
#define INDIM   16
#define HDIM    64
#define SEQLEN  100
#define MEANS_N (BTOT * SEQLEN * 4)   // 1638400

// ---------- helpers ----------
__device__ __forceinline__ float sigmoidf_(float x) {
    return __builtin_amdgcn_rcpf(1.0f + __expf(-x));
}
__device__ __forceinline__ float tanhf_(float x) {
    float e = __expf(2.0f * x);
    return 1.0f - 2.0f * __builtin_amdgcn_rcpf(e + 1.0f);
}
// gelu via Abramowitz-Stegun 7.1.26 erf (|err| < 1.5e-7)
__device__ __forceinline__ float gelu_fast(float x) {
    float z = fabsf(x) * 0.70710678118654752440f;
    float t = __builtin_amdgcn_rcpf(1.0f + 0.3275911f * z);
    float p = t * (0.254829592f +
              t * (-0.284496736f +
              t * (1.421413741f +
              t * (-1.453152027f +
              t * 1.061405429f))));
    float er = 1.0f - p * __expf(-z * z);
    er = copysignf(er, x);
    return 0.5f * x * (1.0f + er);
}

// ---------- bf16 split helpers (bf16x3 emulated-fp32 MFMA) ----------
typedef __attribute__((ext_vector_type(8))) short s8v;   // 8 bf16 (4 VGPRs)
typedef __attribute__((ext_vector_type(4))) float f4v;   // 4 fp32
typedef unsigned short ush;

__device__ __forceinline__ float bf2f(ush b) {
    return __uint_as_float(((unsigned)b) << 16);
}
// RNE pair-convert via v_cvt_pk_bf16_f32 (R10: replaces 4-op bit-math f2bf;
// RNE == RNE -> bitwise-identical results)
__device__ __forceinline__ ushort2 cvt2bf(float x, float y) {
    __hip_bfloat162 h2 = __float22bfloat162_rn(make_float2(x, y));
    return make_ushort2(__bfloat16_as_ushort(h2.x), __bfloat16_as_ushort(h2.y));
}
__device__ __forceinline__ ush f2bf(float x) {
    return __bfloat16_as_ushort(__float2bfloat16(x));
}
__device__ __forceinline__ void split2(float4 a, float4 b, s8v& hi, s8v& lo) {
    float v[8] = {a.x, a.y, a.z, a.w, b.x, b.y, b.z, b.w};
    #pragma unroll
    for (int j = 0; j < 8; j += 2) {
        ushort2 h = cvt2bf(v[j], v[j + 1]);
        ushort2 l = cvt2bf(v[j] - bf2f(h.x), v[j + 1] - bf2f(h.y));
        hi[j] = (short)h.x; hi[j + 1] = (short)h.y;
        lo[j] = (short)l.x; lo[j + 1] = (short)l.y;
    }
}
__device__ __forceinline__ void split8(const float* v, s8v& hi, s8v& lo) {
    #pragma unroll
    for (int j = 0; j < 8; j += 2) {
        ushort2 h = cvt2bf(v[j], v[j + 1]);
        ushort2 l = cvt2bf(v[j] - bf2f(h.x), v[j + 1] - bf2f(h.y));
        hi[j] = (short)h.x; hi[j + 1] = (short)h.y;
        lo[j] = (short)l.x; lo[j + 1] = (short)l.y;
    }
}
__device__ __forceinline__ void load_bfrag(const float* p, s8v& hi, s8v& lo) {
    float4 a = *(const float4*)p;
    float4 b = *(const float4*)(p + 4);
    split2(a, b, hi, lo);
}

// permlane32_swap merge: lanes 0-31 keep own_lo, lanes 32-63 get send_hi
typedef __attribute__((ext_vector_type(2))) unsigned int u2v;
__device__ __forceinline__ float half_merge(float own_lo, float send_hi) {
    u2v r = __builtin_amdgcn_permlane32_swap(__float_as_uint(own_lo),
                                             __float_as_uint(send_hi),
                                             false, false);
    return __uint_as_float(r[0]);
}

#define MFMA16(a, b, c) __builtin_amdgcn_mfma_f32_16x16x32_bf16((a), (b), (c), 0, 0, 0)

// =====================================================================
// FULLY FUSED enc + dec + heads, SEQUENTIAL phases (R9 structure).
// R10: all bf16 splits via v_cvt_pk_bf16_f32 (RNE, 1 inst per pair) —
// cuts the dominant VALU cost (issue-saturation: MFMA+VALU fill the
// SIMD); unroll-2 on the recurrence loops for literal parity indexing.
// =====================================================================
__global__ __launch_bounds__(256, 2) void fused_all_kernel(
    const float* __restrict__ x,
    const float* __restrict__ eWih, const float* __restrict__ ebih,
    const float* __restrict__ eWhh, const float* __restrict__ ebhh,
    const float* __restrict__ dWih, const float* __restrict__ dbih,
    const float* __restrict__ dWhh, const float* __restrict__ dbhh,
    const float* __restrict__ outW, const float* __restrict__ outb,
    const float* __restrict__ embW, const float* __restrict__ embb,
    const float* __restrict__ trg,
    const float* __restrict__ mW1, const float* __restrict__ mb1,
    const float* __restrict__ mW2, const float* __restrict__ mb2,
    const float* __restrict__ cW1, const float* __restrict__ cb1,
    const float* __restrict__ cW2, const float* __restrict__ cb2,
    float* __restrict__ out)
{
    const int tid  = threadIdx.x;
    const int lane = tid & 63;
    const int w    = tid >> 6;     // wave 0..3
    const int col  = lane & 15;
    const int q    = lane >> 4;
    const int u    = w * 16 + col;
    const int b0   = blockIdx.x * 8;
    // post-rebalance batch row for item j: rows {0,1},{4,5},{2,3},{6,7} for q=0..3
    const int rj0  = (q & 1) * 4 + ((q >> 1) << 1);

    // ---- aliased LDS regions ----
    __shared__ __align__(16) char regA_c[9216];    // hiL+loL  | phase3 H bufs
    __shared__ __align__(16) char regB_c[64000];   // enc x    | o_all[800][20]
    __shared__ __align__(16) float outW_l[16][64];
    __shared__ float init_l[8][16];

    ush (*hiL)[16][72] = (ush(*)[16][72])regA_c;            // [2][16][72]
    ush (*loL)[16][72] = (ush(*)[16][72])(regA_c + 4608);
    ush (*xhi_l)[9][16] = (ush(*)[9][16])regB_c;            // [64][9][16]
    ush (*xlo_l)[9][16] = (ush(*)[9][16])(regB_c + 18432);
    float (*o_all)[20] = (float(*)[20])regB_c;              // [800][20]
    // phase-3 H buffers (valid only after dec loop; alias hiL/loL)
    ush (*Hm_hi)[72] = (ush(*)[72])regA_c;                  // [16][72]
    ush (*Hm_lo)[72] = (ush(*)[72])(regA_c + 2304);
    ush (*Hc_hi)[72] = (ush(*)[72])(regA_c + 4608);
    ush (*Hc_lo)[72] = (ush(*)[72])(regA_c + 6912);

    // ---- stage dec LDS (outW, init_in) ----
    for (int i = tid; i < 16 * 64; i += 256) outW_l[i >> 6][i & 63] = outW[i];
    if (tid < 128) {
        int b = tid >> 4, jj = tid & 15;
        float s = embb[jj];
        #pragma unroll
        for (int s4 = 0; s4 < 4; ++s4)
            s = fmaf(embW[jj * 4 + s4], trg[(size_t)(b0 + b) * 4 + s4], s);
        init_l[b][jj] = s;
    }

    // ---- enc init: zero both h buffers (rows 8-15 stay zero forever) ----
    for (int i = tid; i < 4608; i += 256) ((ush*)regA_c)[i] = 0;
    for (int i = tid; i < 64 * 16; i += 256) {
        xhi_l[i >> 4][8][i & 15] = 0;
        xlo_l[i >> 4][8][i & 15] = 0;
    }

    // stage one 64-step chunk of x, pre-split into bf16 hi/lo
    auto stage_x = [&](int c) {
        #pragma unroll
        for (int k = 0; k < 8; ++k) {
            int f   = tid + k * 256;
            int b   = f >> 8;
            int rem = f & 255;
            int tl  = rem >> 2;
            int d4  = (rem & 3) << 2;
            const float* xp = x + ((size_t)(b0 + b) * SRCLEN + (c * 64 + tl)) * INDIM + d4;
            float4 v = *(const float4*)xp;
            ushort2 h01 = cvt2bf(v.x, v.y);
            ushort2 h23 = cvt2bf(v.z, v.w);
            ushort2 l01 = cvt2bf(v.x - bf2f(h01.x), v.y - bf2f(h01.y));
            ushort2 l23 = cvt2bf(v.z - bf2f(h23.x), v.w - bf2f(h23.y));
            *(ushort4*)&xhi_l[tl][b][d4] = make_ushort4(h01.x, h01.y, h23.x, h23.y);
            *(ushort4*)&xlo_l[tl][b][d4] = make_ushort4(l01.x, l01.y, l23.x, l23.y);
        }
    };

    const s8v z8 = {0, 0, 0, 0, 0, 0, 0, 0};
    const f4v z4 = {0.0f, 0.0f, 0.0f, 0.0f};

    // ================= PHASE 1: ENCODER =================
    float hold2e[2];
    {
        s8v brh[3], brl[3], bzh[3], bzl[3], bnhh[2], bnhl[2], bnxh, bnxl;
        load_bfrag(eWhh + (size_t)u * 64 + q * 8,              brh[0], brl[0]);
        load_bfrag(eWhh + (size_t)u * 64 + 32 + q * 8,         brh[1], brl[1]);
        load_bfrag(eWhh + (size_t)(64 + u) * 64 + q * 8,       bzh[0], bzl[0]);
        load_bfrag(eWhh + (size_t)(64 + u) * 64 + 32 + q * 8,  bzh[1], bzl[1]);
        load_bfrag(eWhh + (size_t)(128 + u) * 64 + q * 8,      bnhh[0], bnhl[0]);
        load_bfrag(eWhh + (size_t)(128 + u) * 64 + 32 + q * 8, bnhh[1], bnhl[1]);
        if (q < 2) {
            load_bfrag(eWih + (size_t)u * 16 + q * 8,         brh[2], brl[2]);
            load_bfrag(eWih + (size_t)(64 + u) * 16 + q * 8,  bzh[2], bzl[2]);
            load_bfrag(eWih + (size_t)(128 + u) * 16 + q * 8, bnxh, bnxl);
        } else {
            brh[2] = z8; brl[2] = z8; bzh[2] = z8; bzl[2] = z8; bnxh = z8; bnxl = z8;
        }

        const float br   = ebih[u] + ebhh[u];
        const float bz   = ebih[u + 64] + ebhh[u + 64];
        const float bnx  = ebih[u + 128];
        const float bnh  = ebhh[u + 128];

        const int xb   = (q < 2) ? (col & 7) : 8;
        const int xoff = (q & 1) * 8;
        const ush* xh_base = &xhi_l[0][xb][xoff];
        const ush* xl_base = &xlo_l[0][xb][xoff];

        stage_x(0);
        hold2e[0] = 0.0f; hold2e[1] = 0.0f;
        __syncthreads();

        int cur = 0;
        #pragma unroll 2
        for (int t = 0; t < SRCLEN; ++t) {
            if (t == 64) {
                stage_x(1);
                __syncthreads();
            }
            const int tl = t & 63;

            const s8v xh = *(const s8v*)(xh_base + (size_t)tl * 144);
            const s8v xl = *(const s8v*)(xl_base + (size_t)tl * 144);

            const s8v ah0 = *(const s8v*)&hiL[cur][col][q * 8];
            const s8v al0 = *(const s8v*)&loL[cur][col][q * 8];
            const s8v ah1 = *(const s8v*)&hiL[cur][col][32 + q * 8];
            const s8v al1 = *(const s8v*)&loL[cur][col][32 + q * 8];

            f4v accr, accz, accnh, accnx;
            accr  = MFMA16(ah0, brh[0], z4);
            accz  = MFMA16(ah0, bzh[0], z4);
            accnh = MFMA16(ah0, bnhh[0], z4);
            accr  = MFMA16(ah0, brl[0], accr);
            accz  = MFMA16(ah0, bzl[0], accz);
            accnh = MFMA16(ah0, bnhl[0], accnh);
            accr  = MFMA16(al0, brh[0], accr);
            accz  = MFMA16(al0, bzh[0], accz);
            accnh = MFMA16(al0, bnhh[0], accnh);
            accr  = MFMA16(ah1, brh[1], accr);
            accz  = MFMA16(ah1, bzh[1], accz);
            accnh = MFMA16(ah1, bnhh[1], accnh);
            accr  = MFMA16(ah1, brl[1], accr);
            accz  = MFMA16(ah1, bzl[1], accz);
            accnh = MFMA16(ah1, bnhl[1], accnh);
            accr  = MFMA16(al1, brh[1], accr);
            accz  = MFMA16(al1, bzh[1], accz);
            accnh = MFMA16(al1, bnhh[1], accnh);
            accr  = MFMA16(xh, brh[2], accr);
            accz  = MFMA16(xh, bzh[2], accz);
            accnx = MFMA16(xh, bnxh, z4);
            accr  = MFMA16(xh, brl[2], accr);
            accz  = MFMA16(xh, bzl[2], accz);
            accnx = MFMA16(xh, bnxl, accnx);
            accr  = MFMA16(xl, brh[2], accr);
            accz  = MFMA16(xl, bzh[2], accz);
            accnx = MFMA16(xl, bnxh, accnx);

            float pr[2], pz[2], pnh[2], pnx[2];
            pr[0]  = half_merge(accr[0],  accr[2]);
            pr[1]  = half_merge(accr[1],  accr[3]);
            pz[0]  = half_merge(accz[0],  accz[2]);
            pz[1]  = half_merge(accz[1],  accz[3]);
            pnh[0] = half_merge(accnh[0], accnh[2]);
            pnh[1] = half_merge(accnh[1], accnh[3]);
            pnx[0] = half_merge(accnx[0], accnx[2]);
            pnx[1] = half_merge(accnx[1], accnx[3]);

            const int nxt = cur ^ 1;
            float h2v[2];
            #pragma unroll
            for (int j = 0; j < 2; ++j) {
                float r  = sigmoidf_(pr[j] + br);
                float zz = sigmoidf_(pz[j] + bz);
                float n  = tanhf_(pnx[j] + bnx + r * (pnh[j] + bnh));
                float h  = (1.0f - zz) * n + zz * hold2e[j];
                hold2e[j] = h;
                h2v[j] = h;
            }
            ushort2 hh = cvt2bf(h2v[0], h2v[1]);
            ushort2 ll = cvt2bf(h2v[0] - bf2f(hh.x), h2v[1] - bf2f(hh.y));
            hiL[nxt][rj0][u]     = hh.x;
            hiL[nxt][rj0 + 1][u] = hh.y;
            loL[nxt][rj0][u]     = ll.x;
            loL[nxt][rj0 + 1][u] = ll.y;
            __syncthreads();
            cur ^= 1;
        }
    }

    // ================= PHASE 2: DECODER (o -> LDS) =========
    {
        float hold2[2] = {hold2e[0], hold2e[1]};

        float wh_r[16], wh_z[16], wh_n[16];
        #pragma unroll
        for (int c = 0; c < 2; ++c)
            #pragma unroll
            for (int jj = 0; jj < 8; ++jj) {
                int k = c * 32 + q * 8 + jj;
                wh_r[c * 8 + jj] = dWhh[(size_t)u * 64 + k];
                wh_z[c * 8 + jj] = dWhh[(size_t)(64 + u) * 64 + k];
                wh_n[c * 8 + jj] = dWhh[(size_t)(128 + u) * 64 + k];
            }
        float wi_r[16], wi_z[16], wi_n[16];
        #pragma unroll
        for (int j = 0; j < 16; ++j) {
            wi_r[j] = dWih[(size_t)u * 16 + j];
            wi_z[j] = dWih[(size_t)(64 + u) * 16 + j];
            wi_n[j] = dWih[(size_t)(128 + u) * 16 + j];
        }

        float m_r[16], m_z[16], c_in[16];
        #pragma unroll
        for (int c = 0; c < 2; ++c)
            #pragma unroll
            for (int jj = 0; jj < 8; ++jj) {
                int k = c * 32 + q * 8 + jj;
                float sr = 0.0f, sz = 0.0f, sn = 0.0f;
                #pragma unroll
                for (int j = 0; j < 16; ++j) {
                    float ow = outW_l[j][k];
                    sr = fmaf(wi_r[j], ow, sr);
                    sz = fmaf(wi_z[j], ow, sz);
                    sn = fmaf(wi_n[j], ow, sn);
                }
                m_r[c * 8 + jj]  = wh_r[c * 8 + jj] + sr;
                m_z[c * 8 + jj]  = wh_z[c * 8 + jj] + sz;
                c_in[c * 8 + jj] = sn;
            }

        s8v mrh[2], mrl[2], mzh[2], mzl[2], cinh[2], cinl[2], hnh[2], hnl[2];
        split8(m_r,      mrh[0],  mrl[0]);  split8(m_r + 8,  mrh[1],  mrl[1]);
        split8(m_z,      mzh[0],  mzl[0]);  split8(m_z + 8,  mzh[1],  mzl[1]);
        split8(c_in,     cinh[0], cinl[0]); split8(c_in + 8, cinh[1], cinl[1]);
        split8(wh_n,     hnh[0],  hnl[0]);  split8(wh_n + 8, hnh[1],  hnl[1]);
        s8v r0h[2], r0l[2], z0h[2], z0l[2];
        split8(wh_r, r0h[0], r0l[0]); split8(wh_r + 8, r0h[1], r0l[1]);
        split8(wh_z, z0h[0], z0l[0]); split8(wh_z + 8, z0h[1], z0l[1]);
        s8v owh[2], owl[2];
        {
            float ov[16];
            #pragma unroll
            for (int c = 0; c < 2; ++c)
                #pragma unroll
                for (int jj = 0; jj < 8; ++jj)
                    ov[c * 8 + jj] = outW_l[col][c * 32 + q * 8 + jj];
            split8(ov, owh[0], owl[0]); split8(ov + 8, owh[1], owl[1]);
        }

        float b_r = dbhh[u] + dbih[u];
        float b_z = dbhh[u + 64] + dbih[u + 64];
        float b_in = dbih[u + 128];
        const float b_hn = dbhh[u + 128];
        #pragma unroll
        for (int j = 0; j < 16; ++j) {
            float obj = outb[j];
            b_r  = fmaf(obj, wi_r[j], b_r);
            b_z  = fmaf(obj, wi_z[j], b_z);
            b_in = fmaf(obj, wi_n[j], b_in);
        }
        const float ob = outb[col];

        float g_r[2], g_z[2], g_n[2];
        #pragma unroll
        for (int j2 = 0; j2 < 2; ++j2) {
            int row = rj0 + j2;
            float sr = dbih[u] + dbhh[u];
            float sz = dbih[u + 64] + dbhh[u + 64];
            float sn = dbih[u + 128];
            #pragma unroll
            for (int j = 0; j < 16; ++j) {
                float iv = init_l[row][j];
                sr = fmaf(wi_r[j], iv, sr);
                sz = fmaf(wi_z[j], iv, sz);
                sn = fmaf(wi_n[j], iv, sn);
            }
            g_r[j2] = sr; g_z[j2] = sz; g_n[j2] = sn;
        }

        // ---- dec step 0: h1 = GRU(h0, init_in); h0 already in buf0 ----
        {
            const s8v ah0 = *(const s8v*)&hiL[0][col][q * 8];
            const s8v al0 = *(const s8v*)&loL[0][col][q * 8];
            const s8v ah1 = *(const s8v*)&hiL[0][col][32 + q * 8];
            const s8v al1 = *(const s8v*)&loL[0][col][32 + q * 8];
            f4v ar, az, ahn;
            ar  = MFMA16(ah0, r0h[0], z4);
            az  = MFMA16(ah0, z0h[0], z4);
            ahn = MFMA16(ah0, hnh[0], z4);
            ar  = MFMA16(ah0, r0l[0], ar);
            az  = MFMA16(ah0, z0l[0], az);
            ahn = MFMA16(ah0, hnl[0], ahn);
            ar  = MFMA16(al0, r0h[0], ar);
            az  = MFMA16(al0, z0h[0], az);
            ahn = MFMA16(al0, hnh[0], ahn);
            ar  = MFMA16(ah1, r0h[1], ar);
            az  = MFMA16(ah1, z0h[1], az);
            ahn = MFMA16(ah1, hnh[1], ahn);
            ar  = MFMA16(ah1, r0l[1], ar);
            az  = MFMA16(ah1, z0l[1], az);
            ahn = MFMA16(ah1, hnl[1], ahn);
            ar  = MFMA16(al1, r0h[1], ar);
            az  = MFMA16(al1, z0h[1], az);
            ahn = MFMA16(al1, hnh[1], ahn);

            float pr[2], pz[2], pnh[2];
            pr[0]  = half_merge(ar[0],  ar[2]);
            pr[1]  = half_merge(ar[1],  ar[3]);
            pz[0]  = half_merge(az[0],  az[2]);
            pz[1]  = half_merge(az[1],  az[3]);
            pnh[0] = half_merge(ahn[0], ahn[2]);
            pnh[1] = half_merge(ahn[1], ahn[3]);

            float h2v[2];
            #pragma unroll
            for (int j = 0; j < 2; ++j) {
                float r  = sigmoidf_(pr[j] + g_r[j]);
                float zz = sigmoidf_(pz[j] + g_z[j]);
                float n  = tanhf_(g_n[j] + r * (pnh[j] + b_hn));
                float h  = (1.0f - zz) * n + zz * hold2[j];
                hold2[j] = h;
                h2v[j] = h;
            }
            ushort2 hh = cvt2bf(h2v[0], h2v[1]);
            ushort2 ll = cvt2bf(h2v[0] - bf2f(hh.x), h2v[1] - bf2f(hh.y));
            hiL[1][rj0][u]     = hh.x;
            hiL[1][rj0 + 1][u] = hh.y;
            loL[1][rj0][u]     = ll.x;
            loL[1][rj0 + 1][u] = ll.y;
            __syncthreads();
        }

        // ---- dec steps 1..99; o_{t-1} (round-robin wave) -> o_all ----
        #pragma unroll 2
        for (int t = 1; t < SEQLEN; ++t) {
            const int dcur = t & 1;
            const s8v ah0 = *(const s8v*)&hiL[dcur][col][q * 8];
            const s8v al0 = *(const s8v*)&loL[dcur][col][q * 8];
            const s8v ah1 = *(const s8v*)&hiL[dcur][col][32 + q * 8];
            const s8v al1 = *(const s8v*)&loL[dcur][col][32 + q * 8];

            if (w == ((t - 1) & 3)) {
                f4v oa;
                oa = MFMA16(ah0, owh[0], z4);
                oa = MFMA16(ah0, owl[0], oa);
                oa = MFMA16(al0, owh[0], oa);
                oa = MFMA16(ah1, owh[1], oa);
                oa = MFMA16(ah1, owl[1], oa);
                oa = MFMA16(al1, owh[1], oa);
                if (q < 2) {
                    #pragma unroll
                    for (int i = 0; i < 4; ++i)
                        o_all[(q * 4 + i) * SEQLEN + (t - 1)][col] = oa[i] + ob;
                }
            }

            f4v ar, az, ain, ahn;
            ar  = MFMA16(ah0, mrh[0], z4);
            az  = MFMA16(ah0, mzh[0], z4);
            ain = MFMA16(ah0, cinh[0], z4);
            ahn = MFMA16(ah0, hnh[0], z4);
            ar  = MFMA16(ah0, mrl[0], ar);
            az  = MFMA16(ah0, mzl[0], az);
            ain = MFMA16(ah0, cinl[0], ain);
            ahn = MFMA16(ah0, hnl[0], ahn);
            ar  = MFMA16(al0, mrh[0], ar);
            az  = MFMA16(al0, mzh[0], az);
            ain = MFMA16(al0, cinh[0], ain);
            ahn = MFMA16(al0, hnh[0], ahn);
            ar  = MFMA16(ah1, mrh[1], ar);
            az  = MFMA16(ah1, mzh[1], az);
            ain = MFMA16(ah1, cinh[1], ain);
            ahn = MFMA16(ah1, hnh[1], ahn);
            ar  = MFMA16(ah1, mrl[1], ar);
            az  = MFMA16(ah1, mzl[1], az);
            ain = MFMA16(ah1, cinl[1], ain);
            ahn = MFMA16(ah1, hnl[1], ahn);
            ar  = MFMA16(al1, mrh[1], ar);
            az  = MFMA16(al1, mzh[1], az);
            ain = MFMA16(al1, cinh[1], ain);
            ahn = MFMA16(al1, hnh[1], ahn);

            float pr[2], pz[2], pin[2], pnh[2];
            pr[0]  = half_merge(ar[0],  ar[2]);
            pr[1]  = half_merge(ar[1],  ar[3]);
            pz[0]  = half_merge(az[0],  az[2]);
            pz[1]  = half_merge(az[1],  az[3]);
            pin[0] = half_merge(ain[0], ain[2]);
            pin[1] = half_merge(ain[1], ain[3]);
            pnh[0] = half_merge(ahn[0], ahn[2]);
            pnh[1] = half_merge(ahn[1], ahn[3]);

            const int nxt = dcur ^ 1;
            float h2v[2];
            #pragma unroll
            for (int j = 0; j < 2; ++j) {
                float r  = sigmoidf_(pr[j] + b_r);
                float zz = sigmoidf_(pz[j] + b_z);
                float n  = tanhf_(pin[j] + b_in + r * (pnh[j] + b_hn));
                float h  = (1.0f - zz) * n + zz * hold2[j];
                hold2[j] = h;
                h2v[j] = h;
            }
            ushort2 hh = cvt2bf(h2v[0], h2v[1]);
            ushort2 ll = cvt2bf(h2v[0] - bf2f(hh.x), h2v[1] - bf2f(hh.y));
            hiL[nxt][rj0][u]     = hh.x;
            hiL[nxt][rj0 + 1][u] = hh.y;
            loL[nxt][rj0][u]     = ll.x;
            loL[nxt][rj0 + 1][u] = ll.y;
            __syncthreads();
        }

        // ---- epilogue: o_99 = h_100 @ outW^T + outb (buf 0) ----
        if (w == 0) {
            const s8v ah0 = *(const s8v*)&hiL[0][col][q * 8];
            const s8v al0 = *(const s8v*)&loL[0][col][q * 8];
            const s8v ah1 = *(const s8v*)&hiL[0][col][32 + q * 8];
            const s8v al1 = *(const s8v*)&loL[0][col][32 + q * 8];
            f4v oa;
            oa = MFMA16(ah0, owh[0], z4);
            oa = MFMA16(ah0, owl[0], oa);
            oa = MFMA16(al0, owh[0], oa);
            oa = MFMA16(ah1, owh[1], oa);
            oa = MFMA16(ah1, owl[1], oa);
            oa = MFMA16(al1, owh[1], oa);
            if (q < 2) {
                #pragma unroll
                for (int i = 0; i < 4; ++i)
                    o_all[(q * 4 + i) * SEQLEN + (SEQLEN - 1)][col] = oa[i] + ob;
            }
        }
    }

    // keep phase-3 weight loads below the dec loop (no hoisting across)
    __builtin_amdgcn_sched_barrier(0);

    // ================= PHASE 3: HEADS (50 tiles x 16 rows) ===========
    {
        // stage1 weights: per-wave c-chunk = w
        s8v w1mh, w1ml, w1ch, w1cl;
        if (q < 2) {
            load_bfrag(mW1 + (size_t)(w * 16 + col) * 16 + q * 8, w1mh, w1ml);
            load_bfrag(cW1 + (size_t)(w * 16 + col) * 16 + q * 8, w1ch, w1cl);
        } else { w1mh = z8; w1ml = z8; w1ch = z8; w1cl = z8; }
        const float b1m = mb1[w * 16 + col];
        const float b1c = cb1[w * 16 + col];
        // stage2 weights: wave 2 = mean head, wave 3 = cov head
        s8v w2h[2], w2l[2];
        w2h[0] = z8; w2l[0] = z8; w2h[1] = z8; w2l[1] = z8;
        float b2 = 0.0f;
        if (w == 2) {
            if (col < 4) {
                load_bfrag(mW2 + (size_t)col * 64 + q * 8,      w2h[0], w2l[0]);
                load_bfrag(mW2 + (size_t)col * 64 + 32 + q * 8, w2h[1], w2l[1]);
                b2 = mb2[col];
            }
        } else if (w == 3) {
            if (col < 10) {
                load_bfrag(cW2 + (size_t)col * 64 + q * 8,      w2h[0], w2l[0]);
                load_bfrag(cW2 + (size_t)col * 64 + 32 + q * 8, w2h[1], w2l[1]);
                b2 = cb2[col];
            }
        }

        float* means = out;
        float* covs  = out + MEANS_N;

        __syncthreads();   // epilogue o-write + hiL last reads done -> H aliases OK

        #pragma unroll 1
        for (int tile = 0; tile < 50; ++tile) {
            const int r0 = tile * 16;

            // ---- stage1: A = o rows (K=16, q<2 real); H cols w*16.. ----
            s8v ah, al;
            if (q < 2) {
                load_bfrag(&o_all[r0 + col][q * 8], ah, al);
            } else { ah = z8; al = z8; }

            f4v am = MFMA16(ah, w1mh, z4);
            am = MFMA16(ah, w1ml, am);
            am = MFMA16(al, w1mh, am);
            f4v ac = MFMA16(ah, w1ch, z4);
            ac = MFMA16(ah, w1cl, ac);
            ac = MFMA16(al, w1ch, ac);

            float hm[4], hc[4];
            #pragma unroll
            for (int i = 0; i < 4; ++i) {
                hm[i] = gelu_fast(am[i] + b1m);
                hc[i] = gelu_fast(ac[i] + b1c);
            }
            #pragma unroll
            for (int i = 0; i < 4; i += 2) {
                ushort2 mh = cvt2bf(hm[i], hm[i + 1]);
                ushort2 ml = cvt2bf(hm[i] - bf2f(mh.x), hm[i + 1] - bf2f(mh.y));
                Hm_hi[q * 4 + i][w * 16 + col]     = mh.x;
                Hm_hi[q * 4 + i + 1][w * 16 + col] = mh.y;
                Hm_lo[q * 4 + i][w * 16 + col]     = ml.x;
                Hm_lo[q * 4 + i + 1][w * 16 + col] = ml.y;
                ushort2 ch = cvt2bf(hc[i], hc[i + 1]);
                ushort2 cl = cvt2bf(hc[i] - bf2f(ch.x), hc[i + 1] - bf2f(ch.y));
                Hc_hi[q * 4 + i][w * 16 + col]     = ch.x;
                Hc_hi[q * 4 + i + 1][w * 16 + col] = ch.y;
                Hc_lo[q * 4 + i][w * 16 + col]     = cl.x;
                Hc_lo[q * 4 + i + 1][w * 16 + col] = cl.y;
            }
            __syncthreads();

            // ---- stage2: out = H @ W2^T + b2 (w2=mean, w3=cov) ----
            if (w >= 2) {
                s8v a0h, a0l, a1h, a1l;
                if (w == 2) {
                    a0h = *(const s8v*)&Hm_hi[col][q * 8];
                    a0l = *(const s8v*)&Hm_lo[col][q * 8];
                    a1h = *(const s8v*)&Hm_hi[col][32 + q * 8];
                    a1l = *(const s8v*)&Hm_lo[col][32 + q * 8];
                } else {
                    a0h = *(const s8v*)&Hc_hi[col][q * 8];
                    a0l = *(const s8v*)&Hc_lo[col][q * 8];
                    a1h = *(const s8v*)&Hc_hi[col][32 + q * 8];
                    a1l = *(const s8v*)&Hc_lo[col][32 + q * 8];
                }

                f4v o2;
                o2 = MFMA16(a0h, w2h[0], z4);
                o2 = MFMA16(a0h, w2l[0], o2);
                o2 = MFMA16(a0l, w2h[0], o2);
                o2 = MFMA16(a1h, w2h[1], o2);
                o2 = MFMA16(a1h, w2l[1], o2);
                o2 = MFMA16(a1l, w2h[1], o2);

                if (w == 2) {
                    if (col < 4) {
                        #pragma unroll
                        for (int i = 0; i < 4; ++i) {
                            int r  = r0 + q * 4 + i;           // 0..799
                            int b  = (r * 41) >> 12;           // r / 100
                            int st = r - b * 100;
                            float v = o2[i] + b2;
                            if (col >= 2) v = fminf(fmaxf(v, -1.0f), 1.0f);
                            means[(size_t)(b0 + b) * (SEQLEN * 4) + st * 4 + col] = v;
                        }
                    }
                } else {
                    if (col < 10) {
                        #pragma unroll
                        for (int i = 0; i < 4; ++i) {
                            int r  = r0 + q * 4 + i;
                            int b  = (r * 41) >> 12;
                            int st = r - b * 100;
                            covs[(size_t)(b0 + b) * (SEQLEN * 10) + st * 10 + col] = o2[i] + b2;
                        }
                    }
                }
            }
            __syncthreads();   // H consumed -> next tile may overwrite
        }
    }
}

// =====================================================================
extern "C" void kernel_launch(void* const* d_in, const int* in_sizes, int n_in,
                              void* d_out, int out_size, void* d_ws, size_t ws_size,
                              hipStream_t stream)
{
    const float* x    = (const float*)d_in[0];
    const float* trg  = (const float*)d_in[1];
    const float* eWih = (const float*)d_in[2];
    const float* ebih = (const float*)d_in[3];
    const float* eWhh = (const float*)d_in[4];
    const float* ebhh = (const float*)d_in[5];
    const float* dWih = (const float*)d_in[6];
    const float* dbih = (const float*)d_in[7];
    const float* dWhh = (const float*)d_in[8];
    const float* dbhh = (const float*)d_in[9];
    const float* outW = (const float*)d_in[10];
    const float* outb = (const float*)d_in[11];
    const float* embW = (const float*)d_in[12];
    const float* embb = (const float*)d_in[13];
    const float* mW1  = (const float*)d_in[14];
    const float* mb1  = (const float*)d_in[15];
    const float* mW2  = (const float*)d_in[16];
    const float* mb2  = (const float*)d_in[17];
    const float* cW1  = (const float*)d_in[18];
    const float* cb1  = (const float*)d_in[19];
    const float* cW2  = (const float*)d_in[20];
    const float* cb2  = (const float*)d_in[21];

    float* outp = (float*)d_out;

    fused_all_kernel<<<dim3(BTOT / 8), dim3(256), 0, stream>>>(
        x, eWih, ebih, eWhh, ebhh, dWih, dbih, dWhh, dbhh,
        outW, outb, embW, embb, trg,
        mW1, mb1, mW2, mb2, cW1, cb1, cW2, cb2, outp);
}